// Round 14
// baseline (346.849 us; speedup 1.0000x reference)
//
#include <hip/hip_runtime.h>
#include <math.h>

// ---------------------------------------------------------------------------
// GCN diffusion forward on MI355X — round 14 (R13 compile-fixed).
//  * fill_bins: NONTEMPORAL pairs reads via long long cast (int2 rejected by
//    the builtin) + 2x grid.
//  * agg64: NONTEMPORAL cs index reads.
//  * zero+convw+temb merged into one prep kernel.
// ---------------------------------------------------------------------------

typedef unsigned short ushortT;
typedef __attribute__((ext_vector_type(8))) short short8v;
typedef __attribute__((ext_vector_type(4))) float f32x4;

#define CSR_CAP 48

__device__ __forceinline__ ushortT f2bf(float f) {
    unsigned int u = __float_as_uint(f);
    u += 0x7FFFu + ((u >> 16) & 1u);     // round-to-nearest-even
    return (ushortT)(u >> 16);
}
__device__ __forceinline__ float bf2f(ushortT u) {
    return __uint_as_float(((unsigned int)u) << 16);
}

// ---- merged prep: zero cnt/flag/bcnt | convw | temb (independent jobs) ----
// blocks [0, nblkN): zero; [nblkN, nblkN+160): convw; last block: temb.
__global__ __launch_bounds__(256) void prep_kernel(int* __restrict__ cnt,
                                                   int* __restrict__ flag,
                                                   int* __restrict__ bcnt, int n, int nblkN,
                                                   const float* __restrict__ w0,
                                                   const float* __restrict__ w1,
                                                   const float* __restrict__ w2,
                                                   const float* __restrict__ w3,
                                                   ushortT* __restrict__ wdst,
                                                   const int* __restrict__ t,
                                                   const float* __restrict__ tw1,
                                                   const float* __restrict__ tb1,
                                                   const float* __restrict__ tw2,
                                                   const float* __restrict__ tb2,
                                                   float* __restrict__ temb) {
    int bid = blockIdx.x;
    if (bid < nblkN) {
        int i = bid * 256 + threadIdx.x;
        if (i < n) { cnt[i] = 0; flag[i] = 0; }
        if (bid == 0 && threadIdx.x < 8) bcnt[threadIdx.x] = 0;
        return;
    }
    if (bid < nblkN + 160) {
        int i = (bid - nblkN) * 256 + threadIdx.x;
        if (i >= 40960) return;
        const float* src; int ST, M, base;
        if (i < 8192)       { src = w0; ST = 8; M = 128; base = 0; }
        else if (i < 16384) { src = w1; ST = 4; M = 64;  base = 8192; }
        else if (i < 24576) { src = w2; ST = 8; M = 128; base = 16384; }
        else                { src = w3; ST = 4; M = 64;  base = 24576; }
        int idx = i - base;
        int j = idx & 7;
        int lane = (idx >> 3) & 63;
        int rest = idx >> 9;
        int s = rest % ST;
        int kq = rest / ST;
        int k = kq * 32 + (lane >> 4) * 8 + j;
        int col = s * 16 + (lane & 15);
        wdst[i] = f2bf(src[(size_t)k * M + col]);
        return;
    }
    // temb block (256 threads; lanes 0-63 active, barriers by all)
    __shared__ float emb[64], hid[64];
    int j = threadIdx.x;
    if (j < 64) {
        float tf = (float)t[0];
        int h = j & 31;
        float freq = expf((float)h * -0.29710775393976190f);  // -ln(10000)/31
        float arg = tf * freq;
        emb[j] = (j < 32) ? sinf(arg) : cosf(arg);
    }
    __syncthreads();
    if (j < 64) {
        float a = tb1[j];
        for (int k = 0; k < 64; ++k) a = fmaf(emb[k], tw1[k * 64 + j], a);
        hid[j] = a / (1.0f + expf(-a));  // SiLU
    }
    __syncthreads();
    if (j < 64) {
        float o = tb2[j];
        for (int k = 0; k < 64; ++k) o = fmaf(hid[k], tw2[k * 64 + j], o);
        temb[j] = o;
    }
}

__global__ __launch_bounds__(256) void flags_kernel(const int* __restrict__ anm, int na,
                                                    const int* __restrict__ nrm, int nn,
                                                    int* __restrict__ flag) {
    int i = blockIdx.x * 256 + threadIdx.x;
    if (i < na) atomicMax(&flag[anm[i]], 1);
    if (i < nn) atomicMax(&flag[nrm[i]], 2);    // norm (2) overrides anm (1)
}

__global__ __launch_bounds__(256) void dinv_kernel(const int* __restrict__ cnt,
                                                   float* __restrict__ dinv, int n) {
    int i = blockIdx.x * 256 + threadIdx.x;
    if (i < n) {
        int c = cnt[i];
        if (c > CSR_CAP) c = CSR_CAP;
        dinv[i] = rsqrtf((float)c + 1.0f);
    }
}

// ---- Phase A: bin edges by dst bucket into 8 contiguous pair arrays ----
__global__ __launch_bounds__(256) void bin_kernel(const int* __restrict__ ei,
                                                  int* __restrict__ bcnt,
                                                  int2* __restrict__ pairs,
                                                  int e, int bdiv, int capb) {
    __shared__ int hist[8];
    __shared__ int base[8];
    __shared__ int cur[8];
    int t = threadIdx.x;
    if (t < 8) { hist[t] = 0; cur[t] = 0; }
    __syncthreads();
    int i0 = blockIdx.x * 2048 + t;
    int bk[8], sr[8], ds[8];
#pragma unroll
    for (int j = 0; j < 8; ++j) {
        int i = i0 + j * 256;
        if (i < e) {
            ds[j] = __builtin_nontemporal_load(ei + e + i);
            sr[j] = __builtin_nontemporal_load(ei + i);
            bk[j] = ds[j] / bdiv;
            atomicAdd(&hist[bk[j]], 1);
        } else bk[j] = -1;
    }
    __syncthreads();
    if (t < 8) base[t] = atomicAdd(&bcnt[t], hist[t]);
    __syncthreads();
#pragma unroll
    for (int j = 0; j < 8; ++j) {
        if (bk[j] >= 0) {
            int p = atomicAdd(&cur[bk[j]], 1);
            pairs[(size_t)bk[j] * capb + base[bk[j]] + p] = make_int2(sr[j], ds[j]);
        }
    }
}

// ---- Phase B: XCD-partitioned scatter from bucket b into padded CSR ----
__global__ __launch_bounds__(256) void fill_bins_kernel(const int2* __restrict__ pairs,
                                                        const int* __restrict__ bcnt,
                                                        int* __restrict__ cnt,
                                                        int* __restrict__ cs, int capb) {
    int b = blockIdx.x & 7;
    int nb = bcnt[b];
    int stride = (gridDim.x >> 3) * 256;
    const long long* pll = (const long long*)pairs;
    for (int i = (blockIdx.x >> 3) * 256 + threadIdx.x; i < nb; i += stride) {
        long long v = __builtin_nontemporal_load(pll + (size_t)b * capb + i);
        int src = (int)(v & 0xFFFFFFFFll);
        int dst = (int)(v >> 32);
        int p = atomicAdd(&cnt[dst], 1);
        if (p < CSR_CAP) cs[(size_t)dst * CSR_CAP + p] = src;
    }
}

// ---- x_t = (noise_x + temb + label_emb[flag]) * dinv[row]  -> bf16 ----
__global__ __launch_bounds__(256) void xt_kernel(const float* __restrict__ nx,
                                                 const float* __restrict__ temb,
                                                 const float* __restrict__ lemb,
                                                 const int* __restrict__ flag,
                                                 const float* __restrict__ dinv,
                                                 ushortT* __restrict__ xt, int n) {
    int t = blockIdx.x * 256 + threadIdx.x;
    int total = n * 16;
    if (t >= total) return;
    int row = t >> 4;
    int c4 = (t & 15) * 4;
    float4 v = *(const float4*)(nx + (size_t)row * 64 + c4);
    float4 tv = *(const float4*)(temb + c4);
    v.x += tv.x; v.y += tv.y; v.z += tv.z; v.w += tv.w;
    int f = flag[row];
    if (f) {
        const float* le = lemb + (f == 1 ? 64 : 0);  // 1->label_emb[1], 2->label_emb[0]
        float4 lv = *(const float4*)(le + c4);
        v.x += lv.x; v.y += lv.y; v.z += lv.z; v.w += lv.w;
    }
    float dv = dinv[row];
    v.x *= dv; v.y *= dv; v.z *= dv; v.w *= dv;
    unsigned int p0 = (unsigned int)f2bf(v.x) | ((unsigned int)f2bf(v.y) << 16);
    unsigned int p1 = (unsigned int)f2bf(v.z) | ((unsigned int)f2bf(v.w) << 16);
    *(uint2*)(xt + (size_t)row * 64 + c4) = make_uint2(p0, p1);
}

// ---------------------------------------------------------------------------
// MFMA GEMM: Y[n][M] = A[n][K] @ W (bf16 in, f32 acc). Wave = 16 rows x M.
// Block = 4 waves = 64 rows. No LDS. SCALE: multiply output row by dinv[row].
// ---------------------------------------------------------------------------
template <int KQT, int ST, bool BIAS_SILU, bool OUT_BF16, bool CAT, bool SCALE>
__global__ __launch_bounds__(256) void mfma_gemm_kernel(const ushortT* __restrict__ A1,
                                                        const ushortT* __restrict__ A2,
                                                        const ushortT* __restrict__ Wswz,
                                                        const float* __restrict__ bias,
                                                        const float* __restrict__ dinvp,
                                                        void* __restrict__ Yv, int n) {
    constexpr int M = ST * 16;
    constexpr int KA = (CAT ? (KQT / 2) : KQT) * 32;   // per-source row stride
    const int lane = threadIdx.x & 63;
    const int wid = threadIdx.x >> 6;
    const int row0 = blockIdx.x * 64 + wid * 16;
    const int arow = row0 + (lane & 15);
    const int kb = (lane >> 4) * 8;

    f32x4 acc[ST];
#pragma unroll
    for (int s = 0; s < ST; ++s) acc[s] = (f32x4){0.f, 0.f, 0.f, 0.f};

#pragma unroll
    for (int kq = 0; kq < KQT; ++kq) {
        const ushortT* Asrc = (CAT && kq >= KQT / 2) ? A2 : A1;
        const int kloc = (CAT && kq >= KQT / 2) ? (kq - KQT / 2) * 32 : kq * 32;
        short8v a = *(const short8v*)(Asrc + (size_t)arow * KA + kloc + kb);
        const ushortT* wp = Wswz + ((size_t)(kq * ST) * 64 + lane) * 8;
#pragma unroll
        for (int s = 0; s < ST; ++s) {
            short8v b = *(const short8v*)(wp + (size_t)s * 64 * 8);
            acc[s] = __builtin_amdgcn_mfma_f32_16x16x32_bf16(a, b, acc[s], 0, 0, 0);
        }
    }

    const int dcol = lane & 15;
    const int drow0 = row0 + (lane >> 4) * 4;
    float sc[4];
    if (SCALE) {
#pragma unroll
        for (int r = 0; r < 4; ++r) sc[r] = (drow0 + r < n) ? dinvp[drow0 + r] : 0.f;
    }
#pragma unroll
    for (int s = 0; s < ST; ++s) {
        float bv = BIAS_SILU ? bias[s * 16 + dcol] : 0.f;
#pragma unroll
        for (int r = 0; r < 4; ++r) {
            int row = drow0 + r;
            if (row >= n) continue;
            float v = acc[s][r];
            if (BIAS_SILU) { v += bv; v = v / (1.0f + expf(-v)); }
            if (SCALE) v *= sc[r];
            if (OUT_BF16) ((ushortT*)Yv)[(size_t)row * M + s * 16 + dcol] = f2bf(v);
            else          ((float*)Yv)[(size_t)row * M + s * 16 + dcol] = v;
        }
    }
}

// ---------------------------------------------------------------------------
// agg over 64-dim PRE-SCALED bf16 rows, padded CSR. TWO nodes per wave:
// joint main loop issues 8+8 independent gathers; drains/tails overlap.
// cs index reads NONTEMPORAL (read-once 19.2MB stream; keep xw in L2).
// out[dst] = dinv[dst]*(sum_src xs[src] + xs[dst]) (+bias,silu,post-scale).
// ---------------------------------------------------------------------------
template <bool BIAS_SILU, bool OUT_BF16, bool POST_SCALE>
__global__ __launch_bounds__(256) void agg64_kernel(const ushortT* __restrict__ xw,
                                                    const int* __restrict__ cnt,
                                                    const int* __restrict__ cs,
                                                    const float* __restrict__ dinv,
                                                    const float* __restrict__ bias,
                                                    void* __restrict__ yv, int n) {
    int pair = (int)(((size_t)blockIdx.x * 256 + threadIdx.x) >> 6);
    int lane = threadIdx.x & 63;
    int nA = pair * 2;
    int nB = nA + 1;
    if (nA >= n) return;
    bool hasB = (nB < n);
    int cA = cnt[nA]; if (cA > CSR_CAP) cA = CSR_CAP;
    int cB = hasB ? cnt[nB] : 0; if (cB > CSR_CAP) cB = CSR_CAP;
    int eA = nA * CSR_CAP, eA1 = eA + cA;
    int eB = hasB ? nB * CSR_CAP : 0;
    int eB1 = eB + cB;

    float a0 = 0.f, a1 = 0.f, a2 = 0.f, a3 = 0.f;
    float b0 = 0.f, b1 = 0.f, b2 = 0.f, b3 = 0.f;

#define CSL(p) __builtin_nontemporal_load(cs + (p))
    // joint phase: 16 gathers in flight
    for (; eA + 8 <= eA1 && eB + 8 <= eB1; eA += 8, eB += 8) {
        int ca0 = CSL(eA),     ca1 = CSL(eA + 1), ca2 = CSL(eA + 2), ca3 = CSL(eA + 3);
        int ca4 = CSL(eA + 4), ca5 = CSL(eA + 5), ca6 = CSL(eA + 6), ca7 = CSL(eA + 7);
        int cb0 = CSL(eB),     cb1 = CSL(eB + 1), cb2 = CSL(eB + 2), cb3 = CSL(eB + 3);
        int cb4 = CSL(eB + 4), cb5 = CSL(eB + 5), cb6 = CSL(eB + 6), cb7 = CSL(eB + 7);
        float va0 = bf2f(xw[(size_t)ca0 * 64 + lane]);
        float va1 = bf2f(xw[(size_t)ca1 * 64 + lane]);
        float va2 = bf2f(xw[(size_t)ca2 * 64 + lane]);
        float va3 = bf2f(xw[(size_t)ca3 * 64 + lane]);
        float va4 = bf2f(xw[(size_t)ca4 * 64 + lane]);
        float va5 = bf2f(xw[(size_t)ca5 * 64 + lane]);
        float va6 = bf2f(xw[(size_t)ca6 * 64 + lane]);
        float va7 = bf2f(xw[(size_t)ca7 * 64 + lane]);
        float vb0 = bf2f(xw[(size_t)cb0 * 64 + lane]);
        float vb1 = bf2f(xw[(size_t)cb1 * 64 + lane]);
        float vb2 = bf2f(xw[(size_t)cb2 * 64 + lane]);
        float vb3 = bf2f(xw[(size_t)cb3 * 64 + lane]);
        float vb4 = bf2f(xw[(size_t)cb4 * 64 + lane]);
        float vb5 = bf2f(xw[(size_t)cb5 * 64 + lane]);
        float vb6 = bf2f(xw[(size_t)cb6 * 64 + lane]);
        float vb7 = bf2f(xw[(size_t)cb7 * 64 + lane]);
        a0 += va0 + va4; a1 += va1 + va5; a2 += va2 + va6; a3 += va3 + va7;
        b0 += vb0 + vb4; b1 += vb1 + vb5; b2 += vb2 + vb6; b3 += vb3 + vb7;
    }
    // drain A / drain B (unroll 8)
    for (; eA + 8 <= eA1; eA += 8) {
        int c0 = CSL(eA),     c1 = CSL(eA + 1), c2 = CSL(eA + 2), c3 = CSL(eA + 3);
        int c4 = CSL(eA + 4), c5 = CSL(eA + 5), c6 = CSL(eA + 6), c7 = CSL(eA + 7);
        a0 += bf2f(xw[(size_t)c0 * 64 + lane]);
        a1 += bf2f(xw[(size_t)c1 * 64 + lane]);
        a2 += bf2f(xw[(size_t)c2 * 64 + lane]);
        a3 += bf2f(xw[(size_t)c3 * 64 + lane]);
        a0 += bf2f(xw[(size_t)c4 * 64 + lane]);
        a1 += bf2f(xw[(size_t)c5 * 64 + lane]);
        a2 += bf2f(xw[(size_t)c6 * 64 + lane]);
        a3 += bf2f(xw[(size_t)c7 * 64 + lane]);
    }
    for (; eB + 8 <= eB1; eB += 8) {
        int c0 = CSL(eB),     c1 = CSL(eB + 1), c2 = CSL(eB + 2), c3 = CSL(eB + 3);
        int c4 = CSL(eB + 4), c5 = CSL(eB + 5), c6 = CSL(eB + 6), c7 = CSL(eB + 7);
        b0 += bf2f(xw[(size_t)c0 * 64 + lane]);
        b1 += bf2f(xw[(size_t)c1 * 64 + lane]);
        b2 += bf2f(xw[(size_t)c2 * 64 + lane]);
        b3 += bf2f(xw[(size_t)c3 * 64 + lane]);
        b0 += bf2f(xw[(size_t)c4 * 64 + lane]);
        b1 += bf2f(xw[(size_t)c5 * 64 + lane]);
        b2 += bf2f(xw[(size_t)c6 * 64 + lane]);
        b3 += bf2f(xw[(size_t)c7 * 64 + lane]);
    }
    // joint 4-tails
    {
        bool tA = (eA + 4 <= eA1), tB = (eB + 4 <= eB1);
        if (tA && tB) {
            int c0 = CSL(eA), c1 = CSL(eA + 1), c2 = CSL(eA + 2), c3 = CSL(eA + 3);
            int d0 = CSL(eB), d1 = CSL(eB + 1), d2 = CSL(eB + 2), d3 = CSL(eB + 3);
            a0 += bf2f(xw[(size_t)c0 * 64 + lane]);
            a1 += bf2f(xw[(size_t)c1 * 64 + lane]);
            a2 += bf2f(xw[(size_t)c2 * 64 + lane]);
            a3 += bf2f(xw[(size_t)c3 * 64 + lane]);
            b0 += bf2f(xw[(size_t)d0 * 64 + lane]);
            b1 += bf2f(xw[(size_t)d1 * 64 + lane]);
            b2 += bf2f(xw[(size_t)d2 * 64 + lane]);
            b3 += bf2f(xw[(size_t)d3 * 64 + lane]);
            eA += 4; eB += 4;
        } else if (tA) {
            int c0 = CSL(eA), c1 = CSL(eA + 1), c2 = CSL(eA + 2), c3 = CSL(eA + 3);
            a0 += bf2f(xw[(size_t)c0 * 64 + lane]);
            a1 += bf2f(xw[(size_t)c1 * 64 + lane]);
            a2 += bf2f(xw[(size_t)c2 * 64 + lane]);
            a3 += bf2f(xw[(size_t)c3 * 64 + lane]);
            eA += 4;
        } else if (tB) {
            int d0 = CSL(eB), d1 = CSL(eB + 1), d2 = CSL(eB + 2), d3 = CSL(eB + 3);
            b0 += bf2f(xw[(size_t)d0 * 64 + lane]);
            b1 += bf2f(xw[(size_t)d1 * 64 + lane]);
            b2 += bf2f(xw[(size_t)d2 * 64 + lane]);
            b3 += bf2f(xw[(size_t)d3 * 64 + lane]);
            eB += 4;
        }
    }
    // singles, interleaved
    for (; eA < eA1 && eB < eB1; ++eA, ++eB) {
        int c = CSL(eA), d = CSL(eB);
        a0 += bf2f(xw[(size_t)c * 64 + lane]);
        b0 += bf2f(xw[(size_t)d * 64 + lane]);
    }
    for (; eA < eA1; ++eA) a0 += bf2f(xw[(size_t)CSL(eA) * 64 + lane]);
    for (; eB < eB1; ++eB) b0 += bf2f(xw[(size_t)CSL(eB) * 64 + lane]);
#undef CSL

    // epilogue A
    {
        float di = dinv[nA];
        float acc = (a0 + a1) + (a2 + a3);
        acc += bf2f(xw[(size_t)nA * 64 + lane]);
        acc *= di;
        if (BIAS_SILU) {
            acc += bias[lane];
            acc = acc / (1.0f + expf(-acc));
        }
        if (POST_SCALE) acc *= di;
        if (OUT_BF16) ((ushortT*)yv)[(size_t)nA * 64 + lane] = f2bf(acc);
        else          ((float*)yv)[(size_t)nA * 64 + lane] = acc;
    }
    // epilogue B
    if (hasB) {
        float di = dinv[nB];
        float acc = (b0 + b1) + (b2 + b3);
        acc += bf2f(xw[(size_t)nB * 64 + lane]);
        acc *= di;
        if (BIAS_SILU) {
            acc += bias[lane];
            acc = acc / (1.0f + expf(-acc));
        }
        if (POST_SCALE) acc *= di;
        if (OUT_BF16) ((ushortT*)yv)[(size_t)nB * 64 + lane] = f2bf(acc);
        else          ((float*)yv)[(size_t)nB * 64 + lane] = acc;
    }
}

extern "C" void kernel_launch(void* const* d_in, const int* in_sizes, int n_in,
                              void* d_out, int out_size, void* d_ws, size_t ws_size,
                              hipStream_t stream) {
    const float* noise_x = (const float*)d_in[0];
    const int*   edge    = (const int*)d_in[1];
    const int*   tptr    = (const int*)d_in[2];
    const int*   anm     = (const int*)d_in[3];
    const int*   nrm     = (const int*)d_in[4];
    const float* tw1     = (const float*)d_in[5];
    const float* tb1     = (const float*)d_in[6];
    const float* tw2     = (const float*)d_in[7];
    const float* tb2     = (const float*)d_in[8];
    const float* lemb    = (const float*)d_in[9];
    const float* w0      = (const float*)d_in[10];
    const float* b0      = (const float*)d_in[11];
    const float* w1      = (const float*)d_in[12];
    const float* b1      = (const float*)d_in[13];
    const float* w2      = (const float*)d_in[14];
    const float* b2      = (const float*)d_in[15];
    const float* w3      = (const float*)d_in[16];
    const float* b3      = (const float*)d_in[17];

    const int N = in_sizes[0] / 64;
    const int E = in_sizes[1] / 2;
    const int na = in_sizes[3];
    const int nn = in_sizes[4];
    float* out = (float*)d_out;

    // workspace carve-out (256B aligned)
    char* ws = (char*)d_ws;
    size_t o = 0;
    auto carve = [&](size_t bytes) -> char* {
        char* p = ws + o;
        o += (bytes + 255) & ~(size_t)255;
        return p;
    };
    const int capb = E / 8 + 8192;
    int*     cnt      = (int*)carve((size_t)N * 4);
    int*     flag     = (int*)carve((size_t)N * 4);
    int*     bcnt     = (int*)carve(256);
    int2*    pairs    = (int2*)carve((size_t)capb * 8 * 8);
    int*     cs       = (int*)carve((size_t)N * CSR_CAP * 4);
    float*   dinv     = (float*)carve((size_t)N * 4);
    float*   temb     = (float*)carve(256);
    ushortT* wswz     = (ushortT*)carve(40960 * 2);
    ushortT* bufXT    = (ushortT*)carve((size_t)N * 64 * 2);  // x_t*dinv -> h1s -> h2(lo)
    ushortT* aggX     = (ushortT*)carve((size_t)N * 64 * 2);  // agg0 out -> h2(hi)
    ushortT* h0       = (ushortT*)carve((size_t)N * 128 * 2); // G0 out (live to end)
    ushortT* xw1      = (ushortT*)carve((size_t)N * 64 * 2);  // G1 out -> z3
    ushortT* aggH1    = (ushortT*)carve((size_t)N * 64 * 2);  // agg2 out
    ushortT* h1s      = bufXT;                                 // reuse
    ushortT* h2       = bufXT;                                 // overlays bufXT+aggX
    ushortT* z3       = xw1;                                   // reuse

    const int nblkN = (N + 255) / 256;
    const int nmax = na > nn ? na : nn;
    const int aggBlk = (N + 7) / 8;          // 4 waves x 2 nodes per block
    const int gblk = (N + 63) / 64;          // 64 rows per mfma-gemm block
    const int bdiv = (N + 7) / 8;            // dst bucket size for XCD partition
    const int binBlk = (E + 2047) / 2048;

    prep_kernel<<<nblkN + 161, 256, 0, stream>>>(cnt, flag, bcnt, N, nblkN,
                                                 w0, w1, w2, w3, wswz,
                                                 tptr, tw1, tb1, tw2, tb2, temb);
    flags_kernel<<<(nmax + 255) / 256, 256, 0, stream>>>(anm, na, nrm, nn, flag);
    bin_kernel<<<binBlk, 256, 0, stream>>>(edge, bcnt, pairs, E, bdiv, capb);
    fill_bins_kernel<<<8 * 256, 256, 0, stream>>>(pairs, bcnt, cnt, cs, capb);
    dinv_kernel<<<nblkN, 256, 0, stream>>>(cnt, dinv, N);
    xt_kernel<<<((size_t)N * 16 + 255) / 256, 256, 0, stream>>>(noise_x, temb, lemb, flag, dinv, bufXT, N);

    // conv0: aggX = agg(x_t) [bf16]; h0 = silu(aggX @ w0 + b0) [bf16]
    agg64_kernel<false, true, false><<<aggBlk, 256, 0, stream>>>(bufXT, cnt, cs, dinv, nullptr, aggX, N);
    mfma_gemm_kernel<2, 8, true, true, false, false><<<gblk, 256, 0, stream>>>(aggX, nullptr, wswz, b0, nullptr, h0, N);
    // conv1: xw1 = (h0 @ w1)*dinv [bf16]; h1s = silu(agg+b1)*dinv [bf16]
    mfma_gemm_kernel<4, 4, false, true, false, true><<<gblk, 256, 0, stream>>>(h0, nullptr, wswz + 8192, nullptr, dinv, xw1, N);
    agg64_kernel<true, true, true><<<aggBlk, 256, 0, stream>>>(xw1, cnt, cs, dinv, b1, h1s, N);
    // conv2: aggH1 = agg(h1) [bf16]; h2 = silu(aggH1 @ w2 + b2) [bf16] (overlay)
    agg64_kernel<false, true, false><<<aggBlk, 256, 0, stream>>>(h1s, cnt, cs, dinv, nullptr, aggH1, N);
    mfma_gemm_kernel<2, 8, true, true, false, false><<<gblk, 256, 0, stream>>>(aggH1, nullptr, wswz + 16384, b2, nullptr, h2, N);
    // conv3: z3 = (h2 @ w3a + h0 @ w3b)*dinv [bf16]; out = silu(agg + b3) [f32]
    mfma_gemm_kernel<8, 4, false, true, true, true><<<gblk, 256, 0, stream>>>(h2, h0, wswz + 24576, nullptr, dinv, z3, N);
    agg64_kernel<true, false, false><<<aggBlk, 256, 0, stream>>>(z3, cnt, cs, dinv, b3, out, N);
}

// Round 15
// 292.312 us; speedup vs baseline: 1.1866x; 1.1866x over previous
//
#include <hip/hip_runtime.h>
#include <math.h>

// ---------------------------------------------------------------------------
// GCN diffusion forward on MI355X — round 15.
// vs R11 (best, 310us; R12 binning neutral, R14 NT-cs regression reverted):
//  * SENTINEL-PADDED agg: cs pre-filled with index N (zero row) so each
//    node's first 16 slots are gathered UNCONDITIONALLY (straight-line, no
//    branches/tails). 2 nodes/wave -> 32 loads in flight. Overflow loop only
//    for deg>16 (~3% of nodes). Pad gathers hit one hot L2 line (no fabric).
//  * Direct XCD-partitioned fill_csr (R11), NT edge reads.
//  * prep merges: zero cnt/flag | preset cs=N | convw | temb+zero-rows.
// ---------------------------------------------------------------------------

typedef unsigned short ushortT;
typedef __attribute__((ext_vector_type(8))) short short8v;
typedef __attribute__((ext_vector_type(4))) float f32x4;

#define CSR_CAP 48

__device__ __forceinline__ ushortT f2bf(float f) {
    unsigned int u = __float_as_uint(f);
    u += 0x7FFFu + ((u >> 16) & 1u);     // round-to-nearest-even
    return (ushortT)(u >> 16);
}
__device__ __forceinline__ float bf2f(ushortT u) {
    return __uint_as_float(((unsigned int)u) << 16);
}

// ---- merged prep ----
// blocks [0,nblkN): zero cnt/flag
// [nblkN, nblkN+csBlk): preset cs = sentinel N (64B/thread int4 writes)
// [.., +160): convw swizzle
// last: temb + zero gather-rows N of bufXT and xw1
__global__ __launch_bounds__(256) void prep_kernel(int* __restrict__ cnt,
                                                   int* __restrict__ flag,
                                                   int n, int nblkN, int csBlk,
                                                   int* __restrict__ cs,
                                                   const float* __restrict__ w0,
                                                   const float* __restrict__ w1,
                                                   const float* __restrict__ w2,
                                                   const float* __restrict__ w3,
                                                   ushortT* __restrict__ wdst,
                                                   const int* __restrict__ t,
                                                   const float* __restrict__ tw1,
                                                   const float* __restrict__ tb1,
                                                   const float* __restrict__ tw2,
                                                   const float* __restrict__ tb2,
                                                   float* __restrict__ temb,
                                                   ushortT* __restrict__ bufXT,
                                                   ushortT* __restrict__ xw1) {
    int bid = blockIdx.x;
    if (bid < nblkN) {
        int i = bid * 256 + threadIdx.x;
        if (i < n) { cnt[i] = 0; flag[i] = 0; }
        return;
    }
    if (bid < nblkN + csBlk) {
        // each thread writes 4 x int4 = 16 ints of sentinel
        size_t total = (size_t)n * CSR_CAP;
        size_t base = ((size_t)(bid - nblkN) * 256 + threadIdx.x) * 16;
        int4 sv = make_int4(n, n, n, n);
#pragma unroll
        for (int j = 0; j < 4; ++j) {
            size_t p = base + j * 4;
            if (p + 4 <= total) *(int4*)(cs + p) = sv;
            else for (size_t q = p; q < total; ++q) cs[q] = n;
        }
        return;
    }
    if (bid < nblkN + csBlk + 160) {
        int i = (bid - nblkN - csBlk) * 256 + threadIdx.x;
        if (i >= 40960) return;
        const float* src; int ST, M, base;
        if (i < 8192)       { src = w0; ST = 8; M = 128; base = 0; }
        else if (i < 16384) { src = w1; ST = 4; M = 64;  base = 8192; }
        else if (i < 24576) { src = w2; ST = 8; M = 128; base = 16384; }
        else                { src = w3; ST = 4; M = 64;  base = 24576; }
        int idx = i - base;
        int j = idx & 7;
        int lane = (idx >> 3) & 63;
        int rest = idx >> 9;
        int s = rest % ST;
        int kq = rest / ST;
        int k = kq * 32 + (lane >> 4) * 8 + j;
        int col = s * 16 + (lane & 15);
        wdst[i] = f2bf(src[(size_t)k * M + col]);
        return;
    }
    // temb block; threads 64-95/96-127 zero sentinel rows of bufXT / xw1
    __shared__ float emb[64], hid[64];
    int j = threadIdx.x;
    if (j >= 64 && j < 96)  ((unsigned int*)(bufXT + (size_t)n * 64))[j - 64] = 0u;
    if (j >= 96 && j < 128) ((unsigned int*)(xw1 + (size_t)n * 64))[j - 96] = 0u;
    if (j < 64) {
        float tf = (float)t[0];
        int h = j & 31;
        float freq = expf((float)h * -0.29710775393976190f);  // -ln(10000)/31
        float arg = tf * freq;
        emb[j] = (j < 32) ? sinf(arg) : cosf(arg);
    }
    __syncthreads();
    if (j < 64) {
        float a = tb1[j];
        for (int k = 0; k < 64; ++k) a = fmaf(emb[k], tw1[k * 64 + j], a);
        hid[j] = a / (1.0f + expf(-a));  // SiLU
    }
    __syncthreads();
    if (j < 64) {
        float o = tb2[j];
        for (int k = 0; k < 64; ++k) o = fmaf(hid[k], tw2[k * 64 + j], o);
        temb[j] = o;
    }
}

__global__ __launch_bounds__(256) void flags_kernel(const int* __restrict__ anm, int na,
                                                    const int* __restrict__ nrm, int nn,
                                                    int* __restrict__ flag) {
    int i = blockIdx.x * 256 + threadIdx.x;
    if (i < na) atomicMax(&flag[anm[i]], 1);
    if (i < nn) atomicMax(&flag[nrm[i]], 2);    // norm (2) overrides anm (1)
}

__global__ __launch_bounds__(256) void dinv_kernel(const int* __restrict__ cnt,
                                                   float* __restrict__ dinv, int n) {
    int i = blockIdx.x * 256 + threadIdx.x;
    if (i < n) dinv[i] = rsqrtf((float)cnt[i] + 1.0f);
}

// Padded-CSR fill, XCD-partitioned (R11): block handles edge chunk
// (blockIdx>>3); only dst bucket == (blockIdx&7) written. NT edge reads.
__global__ __launch_bounds__(256) void fill_csr_kernel(const int* __restrict__ ei,
                                                       int* __restrict__ cnt,
                                                       int* __restrict__ cs, int e, int bdiv) {
    int xcd = blockIdx.x & 7;
    int i = (blockIdx.x >> 3) * 256 + threadIdx.x;
    if (i >= e) return;
    int dst = __builtin_nontemporal_load(ei + e + i);
    if (dst / bdiv != xcd) return;
    int src = __builtin_nontemporal_load(ei + i);
    int p = atomicAdd(&cnt[dst], 1);
    if (p < CSR_CAP) cs[(size_t)dst * CSR_CAP + p] = src;
}

// ---- x_t = (noise_x + temb + label_emb[flag]) * dinv[row]  -> bf16 ----
__global__ __launch_bounds__(256) void xt_kernel(const float* __restrict__ nx,
                                                 const float* __restrict__ temb,
                                                 const float* __restrict__ lemb,
                                                 const int* __restrict__ flag,
                                                 const float* __restrict__ dinv,
                                                 ushortT* __restrict__ xt, int n) {
    int t = blockIdx.x * 256 + threadIdx.x;
    int total = n * 16;
    if (t >= total) return;
    int row = t >> 4;
    int c4 = (t & 15) * 4;
    float4 v = *(const float4*)(nx + (size_t)row * 64 + c4);
    float4 tv = *(const float4*)(temb + c4);
    v.x += tv.x; v.y += tv.y; v.z += tv.z; v.w += tv.w;
    int f = flag[row];
    if (f) {
        const float* le = lemb + (f == 1 ? 64 : 0);  // 1->label_emb[1], 2->label_emb[0]
        float4 lv = *(const float4*)(le + c4);
        v.x += lv.x; v.y += lv.y; v.z += lv.z; v.w += lv.w;
    }
    float dv = dinv[row];
    v.x *= dv; v.y *= dv; v.z *= dv; v.w *= dv;
    unsigned int p0 = (unsigned int)f2bf(v.x) | ((unsigned int)f2bf(v.y) << 16);
    unsigned int p1 = (unsigned int)f2bf(v.z) | ((unsigned int)f2bf(v.w) << 16);
    *(uint2*)(xt + (size_t)row * 64 + c4) = make_uint2(p0, p1);
}

// ---------------------------------------------------------------------------
// MFMA GEMM: Y[n][M] = A[n][K] @ W (bf16 in, f32 acc). Wave = 16 rows x M.
// Block = 4 waves = 64 rows. No LDS. SCALE: multiply output row by dinv[row].
// ---------------------------------------------------------------------------
template <int KQT, int ST, bool BIAS_SILU, bool OUT_BF16, bool CAT, bool SCALE>
__global__ __launch_bounds__(256) void mfma_gemm_kernel(const ushortT* __restrict__ A1,
                                                        const ushortT* __restrict__ A2,
                                                        const ushortT* __restrict__ Wswz,
                                                        const float* __restrict__ bias,
                                                        const float* __restrict__ dinvp,
                                                        void* __restrict__ Yv, int n) {
    constexpr int M = ST * 16;
    constexpr int KA = (CAT ? (KQT / 2) : KQT) * 32;   // per-source row stride
    const int lane = threadIdx.x & 63;
    const int wid = threadIdx.x >> 6;
    const int row0 = blockIdx.x * 64 + wid * 16;
    const int arow = row0 + (lane & 15);
    const int kb = (lane >> 4) * 8;

    f32x4 acc[ST];
#pragma unroll
    for (int s = 0; s < ST; ++s) acc[s] = (f32x4){0.f, 0.f, 0.f, 0.f};

#pragma unroll
    for (int kq = 0; kq < KQT; ++kq) {
        const ushortT* Asrc = (CAT && kq >= KQT / 2) ? A2 : A1;
        const int kloc = (CAT && kq >= KQT / 2) ? (kq - KQT / 2) * 32 : kq * 32;
        short8v a = *(const short8v*)(Asrc + (size_t)arow * KA + kloc + kb);
        const ushortT* wp = Wswz + ((size_t)(kq * ST) * 64 + lane) * 8;
#pragma unroll
        for (int s = 0; s < ST; ++s) {
            short8v b = *(const short8v*)(wp + (size_t)s * 64 * 8);
            acc[s] = __builtin_amdgcn_mfma_f32_16x16x32_bf16(a, b, acc[s], 0, 0, 0);
        }
    }

    const int dcol = lane & 15;
    const int drow0 = row0 + (lane >> 4) * 4;
    float sc[4];
    if (SCALE) {
#pragma unroll
        for (int r = 0; r < 4; ++r) sc[r] = (drow0 + r < n) ? dinvp[drow0 + r] : 0.f;
    }
#pragma unroll
    for (int s = 0; s < ST; ++s) {
        float bv = BIAS_SILU ? bias[s * 16 + dcol] : 0.f;
#pragma unroll
        for (int r = 0; r < 4; ++r) {
            int row = drow0 + r;
            if (row >= n) continue;
            float v = acc[s][r];
            if (BIAS_SILU) { v += bv; v = v / (1.0f + expf(-v)); }
            if (SCALE) v *= sc[r];
            if (OUT_BF16) ((ushortT*)Yv)[(size_t)row * M + s * 16 + dcol] = f2bf(v);
            else          ((float*)Yv)[(size_t)row * M + s * 16 + dcol] = v;
        }
    }
}

// ---------------------------------------------------------------------------
// Sentinel-padded agg over 64-dim PRE-SCALED bf16 rows. TWO nodes per wave.
// cs rows are padded with index n (xw row n = zeros), so the first 16 slots
// of each node are gathered UNCONDITIONALLY: 32 loads in flight, no tails.
// Overflow loop handles deg>16 (P ~ 3%).
// out[dst] = dinv[dst]*(sum_src xs[src] + xs[dst]) (+bias,silu,post-scale).
// ---------------------------------------------------------------------------
template <bool BIAS_SILU, bool OUT_BF16, bool POST_SCALE>
__global__ __launch_bounds__(256) void agg64_kernel(const ushortT* __restrict__ xw,
                                                    const int* __restrict__ cnt,
                                                    const int* __restrict__ cs,
                                                    const float* __restrict__ dinv,
                                                    const float* __restrict__ bias,
                                                    void* __restrict__ yv, int n) {
    int pair = (int)(((size_t)blockIdx.x * 256 + threadIdx.x) >> 6);
    int lane = threadIdx.x & 63;
    int nA = pair * 2;
    int nB = nA + 1;
    if (nA >= n) return;
    bool hasB = (nB < n);
    const int* rA = cs + (size_t)nA * CSR_CAP;
    const int* rB = cs + (size_t)nB * CSR_CAP;   // nB==n never gathered (hasB guard on use)

    // load all 32 indices (wave-uniform addresses)
    int ia[16], ib[16];
#pragma unroll
    for (int j = 0; j < 16; ++j) ia[j] = rA[j];
#pragma unroll
    for (int j = 0; j < 16; ++j) ib[j] = hasB ? rB[j] : n;

    // 32 unconditional gathers
    float va[16], vb[16];
#pragma unroll
    for (int j = 0; j < 16; ++j) va[j] = bf2f(xw[(size_t)ia[j] * 64 + lane]);
#pragma unroll
    for (int j = 0; j < 16; ++j) vb[j] = bf2f(xw[(size_t)ib[j] * 64 + lane]);

    float a0 = (va[0] + va[1]) + (va[2] + va[3]);
    float a1 = (va[4] + va[5]) + (va[6] + va[7]);
    float a2 = (va[8] + va[9]) + (va[10] + va[11]);
    float a3 = (va[12] + va[13]) + (va[14] + va[15]);
    float b0 = (vb[0] + vb[1]) + (vb[2] + vb[3]);
    float b1 = (vb[4] + vb[5]) + (vb[6] + vb[7]);
    float b2 = (vb[8] + vb[9]) + (vb[10] + vb[11]);
    float b3 = (vb[12] + vb[13]) + (vb[14] + vb[15]);

    // overflow (deg > 16), rare
    int cA = cnt[nA]; if (cA > CSR_CAP) cA = CSR_CAP;
    int cB = hasB ? cnt[nB] : 0; if (cB > CSR_CAP) cB = CSR_CAP;
    for (int j = 16; j < cA; ++j) a0 += bf2f(xw[(size_t)rA[j] * 64 + lane]);
    for (int j = 16; j < cB; ++j) b0 += bf2f(xw[(size_t)rB[j] * 64 + lane]);

    // epilogue A
    {
        float di = dinv[nA];
        float acc = (a0 + a1) + (a2 + a3);
        acc += bf2f(xw[(size_t)nA * 64 + lane]);   // self term (pre-scaled)
        acc *= di;
        if (BIAS_SILU) {
            acc += bias[lane];
            acc = acc / (1.0f + expf(-acc));
        }
        if (POST_SCALE) acc *= di;
        if (OUT_BF16) ((ushortT*)yv)[(size_t)nA * 64 + lane] = f2bf(acc);
        else          ((float*)yv)[(size_t)nA * 64 + lane] = acc;
    }
    // epilogue B
    if (hasB) {
        float di = dinv[nB];
        float acc = (b0 + b1) + (b2 + b3);
        acc += bf2f(xw[(size_t)nB * 64 + lane]);
        acc *= di;
        if (BIAS_SILU) {
            acc += bias[lane];
            acc = acc / (1.0f + expf(-acc));
        }
        if (POST_SCALE) acc *= di;
        if (OUT_BF16) ((ushortT*)yv)[(size_t)nB * 64 + lane] = f2bf(acc);
        else          ((float*)yv)[(size_t)nB * 64 + lane] = acc;
    }
}

extern "C" void kernel_launch(void* const* d_in, const int* in_sizes, int n_in,
                              void* d_out, int out_size, void* d_ws, size_t ws_size,
                              hipStream_t stream) {
    const float* noise_x = (const float*)d_in[0];
    const int*   edge    = (const int*)d_in[1];
    const int*   tptr    = (const int*)d_in[2];
    const int*   anm     = (const int*)d_in[3];
    const int*   nrm     = (const int*)d_in[4];
    const float* tw1     = (const float*)d_in[5];
    const float* tb1     = (const float*)d_in[6];
    const float* tw2     = (const float*)d_in[7];
    const float* tb2     = (const float*)d_in[8];
    const float* lemb    = (const float*)d_in[9];
    const float* w0      = (const float*)d_in[10];
    const float* b0      = (const float*)d_in[11];
    const float* w1      = (const float*)d_in[12];
    const float* b1      = (const float*)d_in[13];
    const float* w2      = (const float*)d_in[14];
    const float* b2      = (const float*)d_in[15];
    const float* w3      = (const float*)d_in[16];
    const float* b3      = (const float*)d_in[17];

    const int N = in_sizes[0] / 64;
    const int E = in_sizes[1] / 2;
    const int na = in_sizes[3];
    const int nn = in_sizes[4];
    float* out = (float*)d_out;

    // workspace carve-out (256B aligned)
    char* ws = (char*)d_ws;
    size_t o = 0;
    auto carve = [&](size_t bytes) -> char* {
        char* p = ws + o;
        o += (bytes + 255) & ~(size_t)255;
        return p;
    };
    int*     cnt      = (int*)carve((size_t)N * 4);
    int*     flag     = (int*)carve((size_t)N * 4);
    int*     cs       = (int*)carve((size_t)N * CSR_CAP * 4);
    float*   dinv     = (float*)carve((size_t)N * 4);
    float*   temb     = (float*)carve(256);
    ushortT* wswz     = (ushortT*)carve(40960 * 2);
    ushortT* bufXT    = (ushortT*)carve((size_t)(N + 1) * 64 * 2); // x_t*dinv -> h1s (+zero row N)
    ushortT* aggX     = (ushortT*)carve((size_t)N * 64 * 2);       // agg0 out
    ushortT* h0       = (ushortT*)carve((size_t)N * 128 * 2);      // G0 out (live to end)
    ushortT* xw1      = (ushortT*)carve((size_t)(N + 1) * 64 * 2); // G1 out -> z3 (+zero row N)
    ushortT* aggH1    = (ushortT*)carve((size_t)N * 64 * 2);       // agg2 out
    ushortT* h2       = (ushortT*)carve((size_t)N * 128 * 2);      // G2 out
    ushortT* h1s      = bufXT;                                      // reuse (row N stays zero)
    ushortT* z3       = xw1;                                        // reuse (row N stays zero)

    const int nblkN = (N + 255) / 256;
    const int nblkE = (E + 255) / 256;
    const int nmax = na > nn ? na : nn;
    const int aggBlk = (N + 7) / 8;          // 4 waves x 2 nodes per block
    const int gblk = (N + 63) / 64;          // 64 rows per mfma-gemm block
    const int bdiv = (N + 7) / 8;            // dst bucket size for XCD partition
    const int csBlk = (int)(((size_t)N * CSR_CAP + 4095) / 4096);  // 16 ints/thread

    prep_kernel<<<nblkN + csBlk + 161, 256, 0, stream>>>(cnt, flag, N, nblkN, csBlk, cs,
                                                         w0, w1, w2, w3, wswz,
                                                         tptr, tw1, tb1, tw2, tb2, temb,
                                                         bufXT, xw1);
    flags_kernel<<<(nmax + 255) / 256, 256, 0, stream>>>(anm, na, nrm, nn, flag);
    fill_csr_kernel<<<8 * nblkE, 256, 0, stream>>>(edge, cnt, cs, E, bdiv);
    dinv_kernel<<<nblkN, 256, 0, stream>>>(cnt, dinv, N);
    xt_kernel<<<((size_t)N * 16 + 255) / 256, 256, 0, stream>>>(noise_x, temb, lemb, flag, dinv, bufXT, N);

    // conv0: aggX = agg(x_t) [bf16]; h0 = silu(aggX @ w0 + b0) [bf16]
    agg64_kernel<false, true, false><<<aggBlk, 256, 0, stream>>>(bufXT, cnt, cs, dinv, nullptr, aggX, N);
    mfma_gemm_kernel<2, 8, true, true, false, false><<<gblk, 256, 0, stream>>>(aggX, nullptr, wswz, b0, nullptr, h0, N);
    // conv1: xw1 = (h0 @ w1)*dinv [bf16]; h1s = silu(agg+b1)*dinv [bf16]
    mfma_gemm_kernel<4, 4, false, true, false, true><<<gblk, 256, 0, stream>>>(h0, nullptr, wswz + 8192, nullptr, dinv, xw1, N);
    agg64_kernel<true, true, true><<<aggBlk, 256, 0, stream>>>(xw1, cnt, cs, dinv, b1, h1s, N);
    // conv2: aggH1 = agg(h1) [bf16]; h2 = silu(aggH1 @ w2 + b2) [bf16]
    agg64_kernel<false, true, false><<<aggBlk, 256, 0, stream>>>(h1s, cnt, cs, dinv, nullptr, aggH1, N);
    mfma_gemm_kernel<2, 8, true, true, false, false><<<gblk, 256, 0, stream>>>(aggH1, nullptr, wswz + 16384, b2, nullptr, h2, N);
    // conv3: z3 = (h2 @ w3a + h0 @ w3b)*dinv [bf16]; out = silu(agg + b3) [f32]
    mfma_gemm_kernel<8, 4, false, true, true, true><<<gblk, 256, 0, stream>>>(h2, h0, wswz + 24576, nullptr, dinv, z3, N);
    agg64_kernel<true, false, false><<<aggBlk, 256, 0, stream>>>(z3, cnt, cs, dinv, b3, out, N);
}